// Round 1
// 153.949 us; speedup vs baseline: 1.1695x; 1.1695x over previous
//
#include <hip/hip_runtime.h>

// BacklashNet: per-row nonlinear scan (backlash/hysteresis), fully fused.
//
// Previous 4-kernel pipeline (sweep0/sweep1/pass_b/pass_c, 180 us) read x from
// HBM 3x with a 256B-stride (uncoalesced, 64 lines/instr) pattern and round-
// tripped 5 MB of aux arrays. Roofline is 128 MB @ 6.3 TB/s ~= 20 us.
//
// New structure: ONE block (128 threads = 2 waves) per row; a row is exactly
// 128 chunks of 64 steps, chunk == thread.
//   1. stage row global->LDS coalesced, XOR-swizzled float4 transpose
//      (slot(c,f) = c*16 + (f ^ (c&15)): 16B-aligned b128, bank-group
//      (f&7)^(c&7) is uniform for every access phase -> conflict-free)
//   2. chunk -> 64 VGPRs (16x ds_read_b128), x lives in registers after this
//   3. pass A: exits e0[c] from guess (p0 for c==0 else 0.0)   [regs only]
//   4. pass B: run from e0[c-1]; write outputs IN-PLACE over the LDS x
//      buffer (x is safe in regs); record exits e1[c]
//   5. acceptance: chunk c+1's pass-B entry equals its true entry iff
//      e0[c]==e1[c] (bitwise). If ALL converge (register compare + ballot),
//      pass B already produced every output from the true entry -> done, no
//      third pass. Rare failure: cooperative stitch with UNIFORM branches
//      (decisions from LDS-broadcast values, identical on all threads); only
//      the owning thread replays its chunk from its own registers and
//      rewrites its column.
//   6. coalesced flush LDS->out (inverse of step 1).
//
// x read once, out written once, zero workspace traffic. Math is bit-exact
// (same __f*_rn bstep, reference op order); acceptance only on bitwise-equal
// entries -> output identical to the serial recurrence.

namespace {

constexpr int kB  = 2048;
constexpr int kT  = 8192;
constexpr int kNC = 128;   // chunks per row == threads per block
// chunk length 64 == kT / kNC

__device__ __forceinline__ float bstep(float xv, float prev, float m_lo, float m_up,
                                       float mlc, float muc) {
  float A1 = __fmul_rn(m_lo, xv);
  float B1 = __fadd_rn(A1, mlc);
  float A2 = __fmul_rn(m_up, xv);
  float B2 = __fadd_rn(A2, muc);
  float C  = __fadd_rn(__fadd_rn(B1, A2), muc);
  float u  = __fsub_rn(prev, A2);
  bool  f1 = (B1 <= prev);
  bool  f2 = (u <= muc);
  float hi = f2 ? C  : B1;
  float lo = f2 ? B2 : prev;
  return f1 ? hi : lo;
}

__global__ __launch_bounds__(128, 2) void backlash_fused(
    const float* __restrict__ x, const float* __restrict__ p0,
    const float* __restrict__ w, float* __restrict__ out) {
  __shared__ float4 sb[kNC * 16];        // 32 KB swizzled transpose buffer
  __shared__ float  se0[kNC], se1[kNC];  // pass-A / pass-B exits
  __shared__ int    sflag[2];            // per-wave all-converged
  __shared__ float  sfix;                // broadcast slot for stitch fixups

  const int r = blockIdx.x;
  const int c = threadIdx.x;             // chunk index within the row
  const float m_lo = w[0], m_up = w[1];
  const float mlc = __fmul_rn(m_lo, w[2]), muc = __fmul_rn(m_up, w[3]);
  const float p0r = p0[r];

  // ---- 1. coalesced stage: global -> LDS (swizzled transpose) ----
  const float4* x4 = reinterpret_cast<const float4*>(x + (size_t)r * kT);
#pragma unroll
  for (int j = 0; j < 16; ++j) {
    const int g  = j * 128 + c;          // contiguous 2 KB per instruction
    const int cc = g >> 4, f = g & 15;
    sb[cc * 16 + (f ^ (cc & 15))] = x4[g];
  }
  __syncthreads();

  // ---- 2. my chunk -> registers (conflict-free b128 column reads) ----
  float4 xb[16];
#pragma unroll
  for (int f = 0; f < 16; ++f) xb[f] = sb[c * 16 + (f ^ (c & 15))];

  // ---- 3. pass A: exit from guess entry ----
  float pa = (c == 0) ? p0r : 0.0f;
#pragma unroll
  for (int q = 0; q < 16; ++q) {
    pa = bstep(xb[q].x, pa, m_lo, m_up, mlc, muc);
    pa = bstep(xb[q].y, pa, m_lo, m_up, mlc, muc);
    pa = bstep(xb[q].z, pa, m_lo, m_up, mlc, muc);
    pa = bstep(xb[q].w, pa, m_lo, m_up, mlc, muc);
  }
  se0[c] = pa;
  __syncthreads();

  // ---- 4. pass B: run from e0[c-1], write outputs in-place ----
  float pb = (c == 0) ? p0r : se0[c - 1];
#pragma unroll
  for (int q = 0; q < 16; ++q) {
    float o0 = bstep(xb[q].x, pb, m_lo, m_up, mlc, muc);
    float o1 = bstep(xb[q].y, o0, m_lo, m_up, mlc, muc);
    float o2 = bstep(xb[q].z, o1, m_lo, m_up, mlc, muc);
    float o3 = bstep(xb[q].w, o2, m_lo, m_up, mlc, muc);
    sb[c * 16 + (q ^ (c & 15))] = make_float4(o0, o1, o2, o3);
    pb = o3;
  }
  se1[c] = pb;

  // ---- 5. acceptance ----
  // chunk c+1 accepts iff e0[c] == e1[c] (its pass-B entry == true entry).
  // c==127's convergence is never consumed -> force true.
  const bool conv = (c == kNC - 1) || (pa == pb);       // register compare
  const unsigned long long bal = __ballot(conv);
  if ((threadIdx.x & 63) == 0) sflag[threadIdx.x >> 6] = (bal == ~0ull);
  __syncthreads();  // publishes se1, sb outputs, and flags

  if (!(sflag[0] && sflag[1])) {
    // Rare exact stitch. All decisions derive from LDS-broadcast values ->
    // identical on every thread -> branches uniform -> barriers legal.
    float t = se1[0];                    // chunk 0 ran from p0: exit exact
    for (int cc = 1; cc < kNC; ++cc) {
      const bool valid = (se0[cc - 1] == t);   // pass-B entry == true entry?
      if (valid) {
        t = se1[cc];
      } else {
        __syncthreads();
        if (c == cc) {                   // owner has x in registers
          float pf = t;
#pragma unroll
          for (int q = 0; q < 16; ++q) {
            float o0 = bstep(xb[q].x, pf, m_lo, m_up, mlc, muc);
            float o1 = bstep(xb[q].y, o0, m_lo, m_up, mlc, muc);
            float o2 = bstep(xb[q].z, o1, m_lo, m_up, mlc, muc);
            float o3 = bstep(xb[q].w, o2, m_lo, m_up, mlc, muc);
            sb[c * 16 + (q ^ (c & 15))] = make_float4(o0, o1, o2, o3);
            pf = o3;
          }
          sfix = pf;
        }
        __syncthreads();
        t = sfix;
      }
    }
    __syncthreads();                     // publish rewritten columns
  }

  // ---- 6. coalesced flush: LDS -> out (inverse transpose) ----
  float4* o4 = reinterpret_cast<float4*>(out + (size_t)r * kT);
#pragma unroll
  for (int j = 0; j < 16; ++j) {
    const int g  = j * 128 + c;
    const int cc = g >> 4, f = g & 15;
    o4[g] = sb[cc * 16 + (f ^ (cc & 15))];
  }
}

}  // namespace

extern "C" void kernel_launch(void* const* d_in, const int* in_sizes, int n_in,
                              void* d_out, int out_size, void* d_ws, size_t ws_size,
                              hipStream_t stream) {
  const float* x  = (const float*)d_in[0];   // (B, T, 1) fp32
  const float* p0 = (const float*)d_in[1];   // (B, 1, 1) fp32
  const float* w  = (const float*)d_in[2];   // (4,) fp32
  float* out = (float*)d_out;                // (B, T, 1) fp32
  (void)in_sizes; (void)n_in; (void)out_size; (void)d_ws; (void)ws_size;

  backlash_fused<<<kB, 128, 0, stream>>>(x, p0, w, out);
}